// Round 12
// baseline (207.107 us; speedup 1.0000x reference)
//
#include <hip/hip_runtime.h>
#include <hip/hip_bf16.h>
#include <cstdint>
#include <cstddef>

#define NEG_SLOPE 0.2f

typedef __attribute__((ext_vector_type(8))) __bf16 bf16x8;
typedef __attribute__((ext_vector_type(4))) __bf16 bf16x4;
typedef __attribute__((ext_vector_type(2))) __bf16 bf16x2;
typedef __attribute__((ext_vector_type(4))) float  f32x4;

__device__ __forceinline__ float lrelu(float v) {
    return (v < 0.f) ? NEG_SLOPE * v : v;
}

// Order-preserving float<->uint key for deterministic atomicMax on floats.
__device__ __forceinline__ unsigned fkey(float x) {
    unsigned b = __float_as_uint(x);
    return b ^ (unsigned)(((int)b >> 31) | 0x80000000);
}
__device__ __forceinline__ float funkey(unsigned k) {
    unsigned b = (k & 0x80000000u) ? (k ^ 0x80000000u) : ~k;
    return __uint_as_float(b);
}

// ---------------------------------------------------------------------------
// FUSED aggregation + layer-1 GEMM. One block = 16 nodes.
// Phase A: 4 waves x 4 nodes each -> two-phase softmax aggregation of x
//          (gmax1 safe-bound max, no per-node max pass), result written to
//          LDS axs[head][node][256] (+4 pad) as bf16.
// Phase B: wave w = head w. MFMA 16-node A-tile (from LDS) x w1t panel
//          (global, L2-hot) -> out1[16][head*128..+128], with bias+relu+bf16
//          store and wsd2-fold partial dots (layer-2 attention scores).
// Kills the 40 MB aggx HBM round-trip entirely.
// ---------------------------------------------------------------------------
__global__ __launch_bounds__(256) void agg_gemm1(
    const __bf16* __restrict__ xb, const int* __restrict__ offs,
    const int* __restrict__ srcs,
    const float* __restrict__ as1_, const float* __restrict__ ad1_,
    const float* __restrict__ gmax1,
    const __bf16* __restrict__ w1t,    // [512][256]
    const float* __restrict__ b1, const float* __restrict__ wsd2,
    __bf16* __restrict__ out1b,        // [N][512]
    float* __restrict__ ps_part, float* __restrict__ pd_part,  // [N][4]
    int N)
{
    __shared__ __bf16 axs[4][16][260];   // [head][node][256 + 4 pad]
    __shared__ float w4s[4][64][4];
    __shared__ int   sidx[4][64];

    const int tid  = threadIdx.x;
    const int wave = tid >> 6, lane = tid & 63;
    const int tile = blockIdx.x * 16;

    // ---- Phase A: aggregate 4 nodes per wave ----
    for (int i = 0; i < 4; ++i) {
        int nn = wave * 4 + i;
        int n  = tile + nn;
        if (n >= N) break;
        int s0 = offs[n], s1 = offs[n + 1];
        float4 adv = *(const float4*)&ad1_[(size_t)n * 4];
        float m0 = lrelu(gmax1[0] + adv.x);
        float m1 = lrelu(gmax1[1] + adv.y);
        float m2 = lrelu(gmax1[2] + adv.z);
        float m3 = lrelu(gmax1[3] + adv.w);

        float d0 = 0.f, d1 = 0.f, d2 = 0.f, d3 = 0.f;
        float a0[4] = {0.f,0.f,0.f,0.f}, a1[4] = {0.f,0.f,0.f,0.f};
        float a2[4] = {0.f,0.f,0.f,0.f}, a3[4] = {0.f,0.f,0.f,0.f};
        const __bf16* xbase = xb + lane * 4;

        for (int base = s0; base < s1; base += 64) {
            int cnt = min(64, s1 - base);
            if (lane < cnt) {
                int s = srcs[base + lane];
                float4 av = *(const float4*)&as1_[(size_t)s * 4];
                float w0 = __expf(lrelu(av.x + adv.x) - m0);
                float w1 = __expf(lrelu(av.y + adv.y) - m1);
                float w2 = __expf(lrelu(av.z + adv.z) - m2);
                float w3 = __expf(lrelu(av.w + adv.w) - m3);
                d0 += w0; d1 += w1; d2 += w2; d3 += w3;
                sidx[wave][lane] = s;
                w4s[wave][lane][0] = w0; w4s[wave][lane][1] = w1;
                w4s[wave][lane][2] = w2; w4s[wave][lane][3] = w3;
            }
            int j = 0;
            for (; j + 7 < cnt; j += 8) {
                int s_[8]; float4 w_[8]; bf16x4 xv_[8];
                #pragma unroll
                for (int q = 0; q < 8; ++q) {
                    s_[q] = sidx[wave][j + q];
                    w_[q] = *(const float4*)&w4s[wave][j + q][0];
                }
                #pragma unroll
                for (int q = 0; q < 8; ++q)
                    xv_[q] = *(const bf16x4*)(xbase + (size_t)s_[q] * 256);
                #pragma unroll
                for (int q = 0; q < 8; ++q) {
                    float xf[4];
                    #pragma unroll
                    for (int c = 0; c < 4; ++c) xf[c] = (float)xv_[q][c];
                    #pragma unroll
                    for (int c = 0; c < 4; ++c) {
                        a0[c] = fmaf(w_[q].x, xf[c], a0[c]);
                        a1[c] = fmaf(w_[q].y, xf[c], a1[c]);
                        a2[c] = fmaf(w_[q].z, xf[c], a2[c]);
                        a3[c] = fmaf(w_[q].w, xf[c], a3[c]);
                    }
                }
            }
            for (; j < cnt; ++j) {
                int s = sidx[wave][j];
                float4 w = *(const float4*)&w4s[wave][j][0];
                bf16x4 xv = *(const bf16x4*)(xbase + (size_t)s * 256);
                float xf[4];
                #pragma unroll
                for (int c = 0; c < 4; ++c) xf[c] = (float)xv[c];
                #pragma unroll
                for (int c = 0; c < 4; ++c) {
                    a0[c] = fmaf(w.x, xf[c], a0[c]);
                    a1[c] = fmaf(w.y, xf[c], a1[c]);
                    a2[c] = fmaf(w.z, xf[c], a2[c]);
                    a3[c] = fmaf(w.w, xf[c], a3[c]);
                }
            }
        }

        #pragma unroll
        for (int t = 1; t < 64; t <<= 1) {
            d0 += __shfl_xor(d0, t);
            d1 += __shfl_xor(d1, t);
            d2 += __shfl_xor(d2, t);
            d3 += __shfl_xor(d3, t);
        }
        float i0 = 1.f / (d0 + 1e-16f);
        float i1 = 1.f / (d1 + 1e-16f);
        float i2 = 1.f / (d2 + 1e-16f);
        float i3 = 1.f / (d3 + 1e-16f);
        bf16x4 o;
        #pragma unroll
        for (int c = 0; c < 4; ++c) o[c] = (__bf16)(a0[c] * i0);
        *(bf16x4*)&axs[0][nn][lane * 4] = o;
        #pragma unroll
        for (int c = 0; c < 4; ++c) o[c] = (__bf16)(a1[c] * i1);
        *(bf16x4*)&axs[1][nn][lane * 4] = o;
        #pragma unroll
        for (int c = 0; c < 4; ++c) o[c] = (__bf16)(a2[c] * i2);
        *(bf16x4*)&axs[2][nn][lane * 4] = o;
        #pragma unroll
        for (int c = 0; c < 4; ++c) o[c] = (__bf16)(a3[c] * i3);
        *(bf16x4*)&axs[3][nn][lane * 4] = o;
    }
    __syncthreads();

    // ---- Phase B: per-wave GEMM, head = wave ----
    const int head = wave;
    const int l15 = lane & 15, kg = lane >> 4;

    f32x4 acc[8];
    #pragma unroll
    for (int nf = 0; nf < 8; ++nf) acc[nf] = (f32x4){0.f, 0.f, 0.f, 0.f};

    #pragma unroll 2
    for (int k0 = 0; k0 < 256; k0 += 32) {
        bf16x4 alo = *(const bf16x4*)&axs[head][l15][k0 + kg * 8];
        bf16x4 ahi = *(const bf16x4*)&axs[head][l15][k0 + kg * 8 + 4];
        bf16x8 af;
        #pragma unroll
        for (int c = 0; c < 4; ++c) { af[c] = alo[c]; af[4 + c] = ahi[c]; }
        bf16x8 bfr[8];
        #pragma unroll
        for (int nf = 0; nf < 8; ++nf)
            bfr[nf] = *(const bf16x8*)(w1t + (size_t)(head * 128 + nf * 16 + l15) * 256 + k0 + kg * 8);
        #pragma unroll
        for (int nf = 0; nf < 8; ++nf)
            acc[nf] = __builtin_amdgcn_mfma_f32_16x16x32_bf16(af, bfr[nf], acc[nf], 0, 0, 0);
    }

    #pragma unroll
    for (int j = 0; j < 4; ++j) {
        int nn = kg * 4 + j;
        int r  = tile + nn;
        float ps = 0.f, pd = 0.f;
        #pragma unroll
        for (int nf = 0; nf < 8; ++nf) {
            int col = head * 128 + nf * 16 + l15;
            float o = fmaxf(acc[nf][j] + b1[col], 0.f);
            if (r < N)
                out1b[(size_t)r * 512 + col] = (__bf16)o;
            ps = fmaf(o, wsd2[col], ps);
            pd = fmaf(o, wsd2[512 + col], pd);
        }
        #pragma unroll
        for (int t = 1; t < 16; t <<= 1) {
            ps += __shfl_xor(ps, t);
            pd += __shfl_xor(pd, t);
        }
        if (l15 == 0 && r < N) {
            ps_part[(size_t)r * 4 + head] = ps;
            pd_part[(size_t)r * 4 + head] = pd;
        }
    }
}

// ---------------------------------------------------------------------------
// Layer-2 GEMM (h2 = out1b @ w2t^T) with sum2 work fused as extra grid rows.
// ---------------------------------------------------------------------------
__global__ __launch_bounds__(256) void gemm2_sum(
    const __bf16* __restrict__ A,      // out1b [M][512]
    const __bf16* __restrict__ Bt,     // w2t [128][512]
    __bf16* __restrict__ Cout,         // h2b [M][128]
    const float* __restrict__ ps_part, const float* __restrict__ pd_part,
    float* __restrict__ as2, float* __restrict__ ad2,
    unsigned* __restrict__ gmax2u,
    int M, int MB)
{
    if ((int)blockIdx.y >= MB) {
        int chunk = ((int)blockIdx.y - MB) * 2 + (int)blockIdx.x;
        int i = chunk * 256 + threadIdx.x;
        float lm = -1e30f;
        if (i < M) {
            float4 p = *(const float4*)&ps_part[(size_t)i * 4];
            float4 q = *(const float4*)&pd_part[(size_t)i * 4];
            float s = (p.x + p.y) + (p.z + p.w);
            float d = (q.x + q.y) + (q.z + q.w);
            as2[i] = s;
            ad2[i] = d;
            lm = s;
        }
        #pragma unroll
        for (int t = 1; t < 64; t <<= 1) lm = fmaxf(lm, __shfl_xor(lm, t));
        if ((threadIdx.x & 63) == 0) atomicMax(gmax2u, fkey(lm));
        return;
    }

    const int tid  = threadIdx.x;
    const int wave = tid >> 6, lane = tid & 63;
    const int wr = wave >> 1, wc = wave & 1;
    const int rowbase = blockIdx.y * 64 + wr * 32;
    const int colbase = blockIdx.x * 64 + wc * 32;
    const int l15 = lane & 15, kg = lane >> 4;
    const int K = 512, N = 128;

    size_t aoff[2], boff[2];
    #pragma unroll
    for (int mf = 0; mf < 2; ++mf) {
        int r = rowbase + mf * 16 + l15;
        if (r > M - 1) r = M - 1;
        aoff[mf] = (size_t)r * K + kg * 8;
    }
    #pragma unroll
    for (int nf = 0; nf < 2; ++nf) {
        int c = colbase + nf * 16 + l15;
        boff[nf] = (size_t)c * K + kg * 8;
    }

    f32x4 acc[2][2];
    #pragma unroll
    for (int mf = 0; mf < 2; ++mf)
        #pragma unroll
        for (int nf = 0; nf < 2; ++nf)
            acc[mf][nf] = (f32x4){0.f, 0.f, 0.f, 0.f};

    #pragma unroll 2
    for (int k0 = 0; k0 < K; k0 += 32) {
        bf16x8 af[2], bfr[2];
        #pragma unroll
        for (int mf = 0; mf < 2; ++mf)
            af[mf] = *(const bf16x8*)(A + aoff[mf] + k0);
        #pragma unroll
        for (int nf = 0; nf < 2; ++nf)
            bfr[nf] = *(const bf16x8*)(Bt + boff[nf] + k0);
        #pragma unroll
        for (int mf = 0; mf < 2; ++mf)
            #pragma unroll
            for (int nf = 0; nf < 2; ++nf)
                acc[mf][nf] = __builtin_amdgcn_mfma_f32_16x16x32_bf16(af[mf], bfr[nf], acc[mf][nf], 0, 0, 0);
    }

    #pragma unroll
    for (int mf = 0; mf < 2; ++mf)
        #pragma unroll
        for (int j = 0; j < 4; ++j) {
            int r = rowbase + mf * 16 + kg * 4 + j;
            if (r < M) {
                #pragma unroll
                for (int nf = 0; nf < 2; ++nf) {
                    int c = colbase + nf * 16 + l15;
                    Cout[(size_t)r * N + c] = (__bf16)acc[mf][nf][j];
                }
            }
        }
}

// ---------------------------------------------------------------------------
// Fused prep: W transpose/convert, attn vectors, gstart, cnt zero, gmax2 init.
// ---------------------------------------------------------------------------
__global__ void prep_kernel(const float* __restrict__ W1, const float* __restrict__ W2,
                            const float* __restrict__ as1w, const float* __restrict__ ad1w,
                            const float* __restrict__ as2w, const float* __restrict__ ad2w,
                            const int* __restrict__ batch,
                            __bf16* __restrict__ w1t, __bf16* __restrict__ w2t,
                            float* __restrict__ wsd1, float* __restrict__ wsd2,
                            int* __restrict__ gstart, int* __restrict__ cnt,
                            unsigned* __restrict__ gmax2u,
                            int N, int G)
{
    int t = blockIdx.x * 256 + threadIdx.x;
    if (t < 131072) {
        int i = t;
        int k = i >> 9, n = i & 511;
        w1t[n * 256 + k] = (__bf16)W1[i];
    } else if (t < 196608) {
        int j = t - 131072;
        int k = j >> 7, n = j & 127;
        w2t[n * 512 + k] = (__bf16)W2[j];
    } else if (t < 199680) {
        int t2 = t - 196608;
        if (t2 < 2048) {
            int k = t2 >> 3, v = t2 & 7, h = v >> 1;
            const float* av = (v & 1) ? (ad1w + h * 128) : (as1w + h * 128);
            float s = 0.f;
            for (int c = 0; c < 128; ++c) s += W1[k * 512 + h * 128 + c] * av[c];
            wsd1[v * 256 + k] = s;
        } else {
            int t3 = t2 - 2048;
            int k = t3 >> 1, v = t3 & 1;
            const float* av = v ? ad2w : as2w;
            float s = 0.f;
            for (int c = 0; c < 128; ++c) s += W2[k * 128 + c] * av[c];
            wsd2[v * 512 + k] = s;
        }
    } else if (t < 199680 + N) {
        int n = t - 199680;
        int b    = batch[n];
        int prev = (n == 0) ? -1 : batch[n - 1];
        for (int g = prev + 1; g <= b; ++g) gstart[g] = n;
        if (n == N - 1) {
            for (int g = b + 1; g <= G; ++g) gstart[g] = N;
        }
    } else if (t < 199680 + 2 * N) {
        cnt[t - 199680 - N] = 0;
    } else if (t == 199680 + 2 * N) {
        *gmax2u = fkey(-1e30f);
    }
}

// ---------------------------------------------------------------------------
// Merged: edge count (2 edges/thread) + x->bf16 conversion + layer-1 scores.
// ---------------------------------------------------------------------------
__global__ __launch_bounds__(256) void count_cvtx(
    const int* __restrict__ ei, int* __restrict__ cnt,
    const float* __restrict__ x, const float* __restrict__ wsd1,
    __bf16* __restrict__ xb, float* __restrict__ as1_, float* __restrict__ ad1_,
    int ET, int E0, int N, int CB)
{
    if ((int)blockIdx.x < CB) {
        int base = (blockIdx.x * 256 + threadIdx.x) * 2;
        #pragma unroll
        for (int k = 0; k < 2; ++k) {
            int e = base + k;
            if (e < ET) {
                int d = (e < E0) ? ei[E0 + e] : (e - E0);
                atomicAdd(&cnt[d], 1);
            }
        }
        return;
    }
    int bid = blockIdx.x - CB;
    int wave = threadIdx.x >> 6, lane = threadIdx.x & 63;
    int n = bid * 4 + wave;
    if (n >= N) return;
    float4 xv = *(const float4*)&x[(size_t)n * 256 + lane * 4];
    bf16x4 xo;
    xo[0] = (__bf16)xv.x; xo[1] = (__bf16)xv.y; xo[2] = (__bf16)xv.z; xo[3] = (__bf16)xv.w;
    *(bf16x4*)&xb[(size_t)n * 256 + lane * 4] = xo;
    float p[8];
    #pragma unroll
    for (int v = 0; v < 8; ++v) {
        float4 wv = *(const float4*)&wsd1[v * 256 + lane * 4];
        p[v] = xv.x * wv.x + xv.y * wv.y + xv.z * wv.z + xv.w * wv.w;
    }
    #pragma unroll
    for (int v = 0; v < 8; ++v)
        #pragma unroll
        for (int s = 1; s < 64; s <<= 1) p[v] += __shfl_xor(p[v], s);
    if (lane == 0) {
        #pragma unroll
        for (int h = 0; h < 4; ++h) {
            as1_[n * 4 + h] = p[2 * h];
            ad1_[n * 4 + h] = p[2 * h + 1];
        }
    }
}

// ---------------------------------------------------------------------------
// Single-block exclusive scan (offs, cur) + global per-head max of as1_.
// ---------------------------------------------------------------------------
__global__ __launch_bounds__(1024) void scan_gmax(
    const int* __restrict__ cnt, int* __restrict__ offs, int* __restrict__ cur,
    const float* __restrict__ as1_, float* __restrict__ gmax1, int n)
{
    constexpr int CHUNK = 20;
    int t = threadIdx.x;
    int base = t * CHUNK;
    int v[CHUNK];
    int s = 0;
    #pragma unroll
    for (int i = 0; i < CHUNK; ++i) {
        int idx = base + i;
        int xv = (idx < n) ? cnt[idx] : 0;
        v[i] = s; s += xv;
    }
    int lane = t & 63, w = t >> 6;
    int sc = s;
    #pragma unroll
    for (int d = 1; d < 64; d <<= 1) {
        int o = __shfl_up(sc, d);
        if (lane >= d) sc += o;
    }
    __shared__ int wt[16], wb[17];
    __shared__ float gsm[16][4];
    if (lane == 63) wt[w] = sc;
    __syncthreads();
    if (t == 0) {
        int acc = 0;
        for (int i = 0; i < 16; ++i) { wb[i] = acc; acc += wt[i]; }
        wb[16] = acc;
    }
    __syncthreads();
    int ebase = wb[w] + (sc - s);
    #pragma unroll
    for (int i = 0; i < CHUNK; ++i) {
        int idx = base + i;
        if (idx < n) {
            int o = ebase + v[i];
            offs[idx] = o;
            cur[idx]  = o;
        }
    }
    if (t == 0) offs[n] = wb[16];

    float lm0 = -1e30f, lm1 = -1e30f, lm2 = -1e30f, lm3 = -1e30f;
    for (int i = t; i < n; i += 1024) {
        float4 a = *(const float4*)&as1_[(size_t)i * 4];
        lm0 = fmaxf(lm0, a.x); lm1 = fmaxf(lm1, a.y);
        lm2 = fmaxf(lm2, a.z); lm3 = fmaxf(lm3, a.w);
    }
    #pragma unroll
    for (int d = 1; d < 64; d <<= 1) {
        lm0 = fmaxf(lm0, __shfl_xor(lm0, d));
        lm1 = fmaxf(lm1, __shfl_xor(lm1, d));
        lm2 = fmaxf(lm2, __shfl_xor(lm2, d));
        lm3 = fmaxf(lm3, __shfl_xor(lm3, d));
    }
    if (lane == 0) {
        gsm[w][0] = lm0; gsm[w][1] = lm1; gsm[w][2] = lm2; gsm[w][3] = lm3;
    }
    __syncthreads();
    if (t == 0) {
        float m0 = -1e30f, m1 = -1e30f, m2 = -1e30f, m3 = -1e30f;
        for (int i = 0; i < 16; ++i) {
            m0 = fmaxf(m0, gsm[i][0]); m1 = fmaxf(m1, gsm[i][1]);
            m2 = fmaxf(m2, gsm[i][2]); m3 = fmaxf(m3, gsm[i][3]);
        }
        gmax1[0] = m0; gmax1[1] = m1; gmax1[2] = m2; gmax1[3] = m3;
    }
}

// ---------------------------------------------------------------------------
// Scatter: store the SOURCE node per CSR slot.
// ---------------------------------------------------------------------------
__global__ void scatter_kernel(const int* __restrict__ ei, int* __restrict__ cur,
                               int* __restrict__ srcs, int ET, int E0)
{
    int e = blockIdx.x * blockDim.x + threadIdx.x;
    if (e >= ET) return;
    int d = (e < E0) ? ei[E0 + e] : (e - E0);
    int s = (e < E0) ? ei[e] : (e - E0);
    int pos = atomicAdd(&cur[d], 1);
    srcs[pos] = s;
}

// ---------------------------------------------------------------------------
// Layer-2 aggregate, two-phase. Safe-bound max from gmax2.
// ---------------------------------------------------------------------------
__global__ __launch_bounds__(256) void aggregate2_kernel(
    const __bf16* __restrict__ h2b, const int* __restrict__ offs,
    const int* __restrict__ srcs,
    const float* __restrict__ as2, const float* __restrict__ ad2,
    const unsigned* __restrict__ gmax2u,
    const float* __restrict__ b2, float* __restrict__ out2, int N)
{
    __shared__ float wls[4][64];
    __shared__ int   sidx[4][64];
    int wave = threadIdx.x >> 6, lane = threadIdx.x & 63;
    int n = blockIdx.x * 4 + wave;
    if (n >= N) return;
    int s0 = offs[n], s1 = offs[n + 1];
    float adn = ad2[n];
    float m = lrelu(funkey(*gmax2u) + adn);

    float den = 0.f;
    float c0 = 0.f, c1 = 0.f;
    const __bf16* hbase = h2b + lane * 2;

    for (int base = s0; base < s1; base += 64) {
        int cnt = min(64, s1 - base);
        if (lane < cnt) {
            int s = srcs[base + lane];
            float w = __expf(lrelu(as2[s] + adn) - m);
            den += w;
            sidx[wave][lane] = s;
            wls[wave][lane]  = w;
        }
        int j = 0;
        for (; j + 7 < cnt; j += 8) {
            int s_[8]; float w_[8]; bf16x2 h_[8];
            #pragma unroll
            for (int i = 0; i < 8; ++i) {
                s_[i] = sidx[wave][j + i];
                w_[i] = wls[wave][j + i];
            }
            #pragma unroll
            for (int i = 0; i < 8; ++i)
                h_[i] = *(const bf16x2*)(hbase + (size_t)s_[i] * 128);
            #pragma unroll
            for (int i = 0; i < 8; ++i) {
                c0 = fmaf(w_[i], (float)h_[i][0], c0);
                c1 = fmaf(w_[i], (float)h_[i][1], c1);
            }
        }
        for (; j < cnt; ++j) {
            int s = sidx[wave][j];
            float w = wls[wave][j];
            bf16x2 hv = *(const bf16x2*)(hbase + (size_t)s * 128);
            c0 = fmaf(w, (float)hv[0], c0);
            c1 = fmaf(w, (float)hv[1], c1);
        }
    }

    #pragma unroll
    for (int t = 1; t < 64; t <<= 1) den += __shfl_xor(den, t);
    float inv = 1.f / (den + 1e-16f);
    float2 o;
    o.x = c0 * inv + b2[lane * 2 + 0];
    o.y = c1 * inv + b2[lane * 2 + 1];
    *(float2*)&out2[(size_t)n * 128 + lane * 2] = o;
}

// ---------------------------------------------------------------------------
// 2-stage mean pool + FC head.
// ---------------------------------------------------------------------------
#define POOL_S 16
__global__ void pool_stage1(const float* __restrict__ out2, const int* __restrict__ gstart,
                            float* __restrict__ partial, int C)
{
    int g = blockIdx.x, slice = blockIdx.y;
    int c = threadIdx.x;
    int s = gstart[g], e = gstart[g + 1];
    int len = e - s;
    int chunk = (len + POOL_S - 1) / POOL_S;
    int n0 = s + slice * chunk;
    int n1 = min(n0 + chunk, e);
    float acc = 0.f;
    for (int n = n0; n < n1; ++n) acc += out2[(size_t)n * C + c];
    partial[((size_t)g * POOL_S + slice) * C + c] = acc;
}

__global__ __launch_bounds__(128) void pool_head(
    const float* __restrict__ partial, const int* __restrict__ gstart,
    const float* __restrict__ fc1W, const float* __restrict__ fc1b,
    const float* __restrict__ fc2W, const float* __restrict__ fc2b,
    float* __restrict__ out)
{
    int g = blockIdx.x;
    int t = threadIdx.x;
    __shared__ float pl[128];
    float acc = 0.f;
    #pragma unroll
    for (int s = 0; s < POOL_S; ++s)
        acc += partial[((size_t)g * POOL_S + s) * 128 + t];
    float cntf = (float)(gstart[g + 1] - gstart[g]);
    pl[t] = acc / fmaxf(cntf, 1.0f);
    __syncthreads();
    if (t < 64) {
        float v = 0.f;
        for (int c = 0; c < 128; ++c)
            v += pl[c] * fc1W[c * 64 + t];
        v = fmaxf(v + fc1b[t], 0.f) * fc2W[t];
        #pragma unroll
        for (int s = 32; s > 0; s >>= 1) v += __shfl_down(v, s);
        if (t == 0) out[g] = v + fc2b[0];
    }
}

// ---------------------------------------------------------------------------
extern "C" void kernel_launch(void* const* d_in, const int* in_sizes, int n_in,
                              void* d_out, int out_size, void* d_ws, size_t ws_size,
                              hipStream_t stream)
{
    const float* x    = (const float*)d_in[0];
    const int*   ei   = (const int*)d_in[1];
    const int*   batch= (const int*)d_in[2];
    const float* W1   = (const float*)d_in[3];
    const float* as1w = (const float*)d_in[4];
    const float* ad1w = (const float*)d_in[5];
    const float* b1   = (const float*)d_in[6];
    const float* W2   = (const float*)d_in[7];
    const float* as2w = (const float*)d_in[8];
    const float* ad2w = (const float*)d_in[9];
    const float* b2   = (const float*)d_in[10];
    const float* fc1W = (const float*)d_in[11];
    const float* fc1b = (const float*)d_in[12];
    const float* fc2W = (const float*)d_in[13];
    const float* fc2b = (const float*)d_in[14];
    float* out = (float*)d_out;

    const int D = 256, C = 128, G = 64;
    const int N  = in_sizes[0] / D;        // 20000
    const int E0 = in_sizes[1] / 2;        // 160000
    const int ET = E0 + N;

    char* p = (char*)d_ws;
    auto alloc = [&](size_t bytes) -> char* {
        char* r = p;
        p += (bytes + 255) & ~(size_t)255;
        return r;
    };
    __bf16* xb    = (__bf16*)alloc((size_t)N * D * 2);
    __bf16* out1b = (__bf16*)alloc((size_t)N * 512 * 2);
    __bf16* h2b   = (__bf16*)alloc((size_t)N * C * 2);
    float*  out2  = (float*)alloc((size_t)N * C * 4);
    __bf16* w1t   = (__bf16*)alloc((size_t)256 * 512 * 2);
    __bf16* w2t   = (__bf16*)alloc((size_t)512 * 128 * 2);
    float* wsd1   = (float*)alloc(8 * 256 * 4);
    float* wsd2   = (float*)alloc(2 * 512 * 4);
    float* gmax1  = (float*)alloc(4 * 4);
    unsigned* gmax2u = (unsigned*)alloc(4);
    float* as1_   = (float*)alloc((size_t)N * 4 * 4);
    float* ad1_   = (float*)alloc((size_t)N * 4 * 4);
    float* ps_part= (float*)alloc((size_t)N * 4 * 4);
    float* pd_part= (float*)alloc((size_t)N * 4 * 4);
    float* as2    = (float*)alloc((size_t)N * 4);
    float* ad2    = (float*)alloc((size_t)N * 4);
    int*   cnt    = (int*)alloc((size_t)N * 4);
    int*   cur    = (int*)alloc((size_t)N * 4);
    int*   offs   = (int*)alloc((size_t)(N + 1) * 4);
    int*   srcs   = (int*)alloc((size_t)ET * 4);
    int*   gstart = (int*)alloc((size_t)(G + 1) * 4);
    float* partial= (float*)alloc((size_t)G * POOL_S * C * 4);

    // 1. prep
    {
        int total = 199680 + 2 * N + 1;
        prep_kernel<<<(total + 255) / 256, 256, 0, stream>>>(
            W1, W2, as1w, ad1w, as2w, ad2w, batch,
            w1t, w2t, wsd1, wsd2, gstart, cnt, gmax2u, N, G);
    }

    // 2. count (2 edges/thread) + cvtx (merged)
    {
        int CB = (ET + 511) / 512;
        count_cvtx<<<CB + N / 4, 256, 0, stream>>>(
            ei, cnt, x, wsd1, xb, as1_, ad1_, ET, E0, N, CB);
    }

    // 3. scan + global head max
    scan_gmax<<<1, 1024, 0, stream>>>(cnt, offs, cur, as1_, gmax1, N);

    // 4. scatter (stores src node per slot)
    scatter_kernel<<<(ET + 255) / 256, 256, 0, stream>>>(ei, cur, srcs, ET, E0);

    // 5. FUSED aggregation + layer-1 GEMM (16 nodes per block)
    agg_gemm1<<<(N + 15) / 16, 256, 0, stream>>>(
        xb, offs, srcs, as1_, ad1_, gmax1, w1t, b1, wsd2,
        out1b, ps_part, pd_part, N);

    // 6. layer-2 GEMM with fused sum2 (extra grid rows)
    {
        int MB = (N + 63) / 64;
        int SB = ((N + 255) / 256 + 1) / 2;
        gemm2_sum<<<dim3(2, MB + SB), 256, 0, stream>>>(
            out1b, w2t, h2b, ps_part, pd_part, as2, ad2, gmax2u, N, MB);
    }

    // 7. layer-2 aggregate (two-phase)
    aggregate2_kernel<<<(N + 3) / 4, 256, 0, stream>>>(
        h2b, offs, srcs, as2, ad2, gmax2u, b2, out2, N);

    // 8. pool + 9. head
    pool_stage1<<<dim3(G, POOL_S), C, 0, stream>>>(out2, gstart, partial, C);
    pool_head<<<G, 128, 0, stream>>>(partial, gstart, fc1W, fc1b, fc2W, fc2b, out);
}

// Round 13
// 203.327 us; speedup vs baseline: 1.0186x; 1.0186x over previous
//
#include <hip/hip_runtime.h>
#include <hip/hip_bf16.h>
#include <cstdint>
#include <cstddef>

#define NEG_SLOPE 0.2f

typedef __attribute__((ext_vector_type(8))) __bf16 bf16x8;
typedef __attribute__((ext_vector_type(4))) __bf16 bf16x4;
typedef __attribute__((ext_vector_type(2))) __bf16 bf16x2;
typedef __attribute__((ext_vector_type(4))) float  f32x4;

__device__ __forceinline__ float lrelu(float v) {
    return (v < 0.f) ? NEG_SLOPE * v : v;
}

// Order-preserving float<->uint key for deterministic atomicMax on floats.
__device__ __forceinline__ unsigned fkey(float x) {
    unsigned b = __float_as_uint(x);
    return b ^ (unsigned)(((int)b >> 31) | 0x80000000);
}
__device__ __forceinline__ float funkey(unsigned k) {
    unsigned b = (k & 0x80000000u) ? (k ^ 0x80000000u) : ~k;
    return __uint_as_float(b);
}

// ---------------------------------------------------------------------------
// Layer-2 GEMM (h2 = out1b @ w2t^T) with sum2 work fused as extra grid rows.
// sum2 collapses ps/pd partials (8 per node: 4 heads x 2 col-halves).
// ---------------------------------------------------------------------------
__global__ __launch_bounds__(256) void gemm2_sum(
    const __bf16* __restrict__ A,      // out1b [M][512]
    const __bf16* __restrict__ Bt,     // w2t [128][512]
    __bf16* __restrict__ Cout,         // h2b [M][128]
    const float* __restrict__ ps_part, const float* __restrict__ pd_part,  // [M][8]
    float* __restrict__ as2, float* __restrict__ ad2,
    unsigned* __restrict__ gmax2u,
    int M, int MB)
{
    if ((int)blockIdx.y >= MB) {
        int chunk = ((int)blockIdx.y - MB) * 2 + (int)blockIdx.x;
        int i = chunk * 256 + threadIdx.x;
        float lm = -1e30f;
        if (i < M) {
            float4 p0 = *(const float4*)&ps_part[(size_t)i * 8];
            float4 p1 = *(const float4*)&ps_part[(size_t)i * 8 + 4];
            float4 q0 = *(const float4*)&pd_part[(size_t)i * 8];
            float4 q1 = *(const float4*)&pd_part[(size_t)i * 8 + 4];
            float s = ((p0.x + p0.y) + (p0.z + p0.w)) + ((p1.x + p1.y) + (p1.z + p1.w));
            float d = ((q0.x + q0.y) + (q0.z + q0.w)) + ((q1.x + q1.y) + (q1.z + q1.w));
            as2[i] = s;
            ad2[i] = d;
            lm = s;
        }
        #pragma unroll
        for (int t = 1; t < 64; t <<= 1) lm = fmaxf(lm, __shfl_xor(lm, t));
        if ((threadIdx.x & 63) == 0) atomicMax(gmax2u, fkey(lm));
        return;
    }

    const int tid  = threadIdx.x;
    const int wave = tid >> 6, lane = tid & 63;
    const int wr = wave >> 1, wc = wave & 1;
    const int rowbase = blockIdx.y * 64 + wr * 32;
    const int colbase = blockIdx.x * 64 + wc * 32;
    const int l15 = lane & 15, kg = lane >> 4;
    const int K = 512, N = 128;

    size_t aoff[2], boff[2];
    #pragma unroll
    for (int mf = 0; mf < 2; ++mf) {
        int r = rowbase + mf * 16 + l15;
        if (r > M - 1) r = M - 1;
        aoff[mf] = (size_t)r * K + kg * 8;
    }
    #pragma unroll
    for (int nf = 0; nf < 2; ++nf) {
        int c = colbase + nf * 16 + l15;
        boff[nf] = (size_t)c * K + kg * 8;
    }

    f32x4 acc[2][2];
    #pragma unroll
    for (int mf = 0; mf < 2; ++mf)
        #pragma unroll
        for (int nf = 0; nf < 2; ++nf)
            acc[mf][nf] = (f32x4){0.f, 0.f, 0.f, 0.f};

    #pragma unroll 2
    for (int k0 = 0; k0 < K; k0 += 32) {
        bf16x8 af[2], bfr[2];
        #pragma unroll
        for (int mf = 0; mf < 2; ++mf)
            af[mf] = *(const bf16x8*)(A + aoff[mf] + k0);
        #pragma unroll
        for (int nf = 0; nf < 2; ++nf)
            bfr[nf] = *(const bf16x8*)(Bt + boff[nf] + k0);
        #pragma unroll
        for (int mf = 0; mf < 2; ++mf)
            #pragma unroll
            for (int nf = 0; nf < 2; ++nf)
                acc[mf][nf] = __builtin_amdgcn_mfma_f32_16x16x32_bf16(af[mf], bfr[nf], acc[mf][nf], 0, 0, 0);
    }

    #pragma unroll
    for (int mf = 0; mf < 2; ++mf)
        #pragma unroll
        for (int j = 0; j < 4; ++j) {
            int r = rowbase + mf * 16 + kg * 4 + j;
            if (r < M) {
                #pragma unroll
                for (int nf = 0; nf < 2; ++nf) {
                    int c = colbase + nf * 16 + l15;
                    Cout[(size_t)r * N + c] = (__bf16)acc[mf][nf][j];
                }
            }
        }
}

// ---------------------------------------------------------------------------
// Layer-1 GEMM on aggregated-x. 64x64 tiles: grid (8 = 4 heads x 2 col-halves,
// ceil(M/64)) = 2504 blocks (~10/CU) for latency hiding; acc = 16 VGPR/thread.
// Epilogue: bias+relu+bf16 store + wsd2-fold partial dots -> ps/pd_part[M][8]
// indexed by head*2+colhalf (summed later in gemm2_sum).
// ---------------------------------------------------------------------------
__global__ __launch_bounds__(256) void gemm1_agg(
    const __bf16* __restrict__ aggx,   // [N][4][256]
    const __bf16* __restrict__ w1t,    // [512][256]
    const float* __restrict__ b1, const float* __restrict__ wsd2,
    __bf16* __restrict__ out1b,        // [N][512]
    float* __restrict__ ps_part, float* __restrict__ pd_part,  // [N][8]
    int M)
{
    const int hc   = blockIdx.x;       // 0..7
    const int head = hc >> 1;
    const int ch   = hc & 1;
    const int tid  = threadIdx.x;
    const int wave = tid >> 6, lane = tid & 63;
    const int wr = wave >> 1, wc = wave & 1;
    const int rowbase = blockIdx.y * 64 + wr * 32;
    const int l15 = lane & 15, kg = lane >> 4;

    size_t aoff[2], boff[2];
    #pragma unroll
    for (int mf = 0; mf < 2; ++mf) {
        int r = rowbase + mf * 16 + l15;
        if (r > M - 1) r = M - 1;
        aoff[mf] = (size_t)r * 1024 + head * 256 + kg * 8;
    }
    #pragma unroll
    for (int nf = 0; nf < 2; ++nf) {
        int c = head * 128 + ch * 64 + wc * 32 + nf * 16 + l15;
        boff[nf] = (size_t)c * 256 + kg * 8;
    }

    f32x4 acc[2][2];
    #pragma unroll
    for (int mf = 0; mf < 2; ++mf)
        #pragma unroll
        for (int nf = 0; nf < 2; ++nf)
            acc[mf][nf] = (f32x4){0.f, 0.f, 0.f, 0.f};

    #pragma unroll 2
    for (int k0 = 0; k0 < 256; k0 += 32) {
        bf16x8 af[2], bfr[2];
        #pragma unroll
        for (int mf = 0; mf < 2; ++mf)
            af[mf] = *(const bf16x8*)(aggx + aoff[mf] + k0);
        #pragma unroll
        for (int nf = 0; nf < 2; ++nf)
            bfr[nf] = *(const bf16x8*)(w1t + boff[nf] + k0);
        #pragma unroll
        for (int mf = 0; mf < 2; ++mf)
            #pragma unroll
            for (int nf = 0; nf < 2; ++nf)
                acc[mf][nf] = __builtin_amdgcn_mfma_f32_16x16x32_bf16(af[mf], bfr[nf], acc[mf][nf], 0, 0, 0);
    }

    __shared__ float smp[2][64], smd[2][64];

    #pragma unroll
    for (int mf = 0; mf < 2; ++mf)
        #pragma unroll
        for (int j = 0; j < 4; ++j) {
            int r = rowbase + mf * 16 + kg * 4 + j;
            float ps = 0.f, pd = 0.f;
            #pragma unroll
            for (int nf = 0; nf < 2; ++nf) {
                int col = head * 128 + ch * 64 + wc * 32 + nf * 16 + l15;
                float o = fmaxf(acc[mf][nf][j] + b1[col], 0.f);
                if (r < M)
                    out1b[(size_t)r * 512 + col] = (__bf16)o;
                ps = fmaf(o, wsd2[col], ps);
                pd = fmaf(o, wsd2[512 + col], pd);
            }
            #pragma unroll
            for (int t = 1; t < 16; t <<= 1) {
                ps += __shfl_xor(ps, t);
                pd += __shfl_xor(pd, t);
            }
            if (l15 == 0) {
                int lr = wr * 32 + mf * 16 + kg * 4 + j;
                smp[wc][lr] = ps;
                smd[wc][lr] = pd;
            }
        }
    __syncthreads();
    if (tid < 64) {
        int r = blockIdx.y * 64 + tid;
        if (r < M) {
            ps_part[(size_t)r * 8 + hc] = smp[0][tid] + smp[1][tid];
            pd_part[(size_t)r * 8 + hc] = smd[0][tid] + smd[1][tid];
        }
    }
}

// ---------------------------------------------------------------------------
// Fused prep: W transpose/convert, attn vectors, gstart, cnt zero, gmax2 init.
// ---------------------------------------------------------------------------
__global__ void prep_kernel(const float* __restrict__ W1, const float* __restrict__ W2,
                            const float* __restrict__ as1w, const float* __restrict__ ad1w,
                            const float* __restrict__ as2w, const float* __restrict__ ad2w,
                            const int* __restrict__ batch,
                            __bf16* __restrict__ w1t, __bf16* __restrict__ w2t,
                            float* __restrict__ wsd1, float* __restrict__ wsd2,
                            int* __restrict__ gstart, int* __restrict__ cnt,
                            unsigned* __restrict__ gmax2u,
                            int N, int G)
{
    int t = blockIdx.x * 256 + threadIdx.x;
    if (t < 131072) {
        int i = t;
        int k = i >> 9, n = i & 511;
        w1t[n * 256 + k] = (__bf16)W1[i];
    } else if (t < 196608) {
        int j = t - 131072;
        int k = j >> 7, n = j & 127;
        w2t[n * 512 + k] = (__bf16)W2[j];
    } else if (t < 199680) {
        int t2 = t - 196608;
        if (t2 < 2048) {
            int k = t2 >> 3, v = t2 & 7, h = v >> 1;
            const float* av = (v & 1) ? (ad1w + h * 128) : (as1w + h * 128);
            float s = 0.f;
            for (int c = 0; c < 128; ++c) s += W1[k * 512 + h * 128 + c] * av[c];
            wsd1[v * 256 + k] = s;
        } else {
            int t3 = t2 - 2048;
            int k = t3 >> 1, v = t3 & 1;
            const float* av = v ? ad2w : as2w;
            float s = 0.f;
            for (int c = 0; c < 128; ++c) s += W2[k * 128 + c] * av[c];
            wsd2[v * 512 + k] = s;
        }
    } else if (t < 199680 + N) {
        int n = t - 199680;
        int b    = batch[n];
        int prev = (n == 0) ? -1 : batch[n - 1];
        for (int g = prev + 1; g <= b; ++g) gstart[g] = n;
        if (n == N - 1) {
            for (int g = b + 1; g <= G; ++g) gstart[g] = N;
        }
    } else if (t < 199680 + 2 * N) {
        cnt[t - 199680 - N] = 0;
    } else if (t == 199680 + 2 * N) {
        *gmax2u = fkey(-1e30f);
    }
}

// ---------------------------------------------------------------------------
// Merged: edge count (2 edges/thread) + x->bf16 conversion + layer-1 scores.
// ---------------------------------------------------------------------------
__global__ __launch_bounds__(256) void count_cvtx(
    const int* __restrict__ ei, int* __restrict__ cnt,
    const float* __restrict__ x, const float* __restrict__ wsd1,
    __bf16* __restrict__ xb, float* __restrict__ as1_, float* __restrict__ ad1_,
    int ET, int E0, int N, int CB)
{
    if ((int)blockIdx.x < CB) {
        int base = (blockIdx.x * 256 + threadIdx.x) * 2;
        #pragma unroll
        for (int k = 0; k < 2; ++k) {
            int e = base + k;
            if (e < ET) {
                int d = (e < E0) ? ei[E0 + e] : (e - E0);
                atomicAdd(&cnt[d], 1);
            }
        }
        return;
    }
    int bid = blockIdx.x - CB;
    int wave = threadIdx.x >> 6, lane = threadIdx.x & 63;
    int n = bid * 4 + wave;
    if (n >= N) return;
    float4 xv = *(const float4*)&x[(size_t)n * 256 + lane * 4];
    bf16x4 xo;
    xo[0] = (__bf16)xv.x; xo[1] = (__bf16)xv.y; xo[2] = (__bf16)xv.z; xo[3] = (__bf16)xv.w;
    *(bf16x4*)&xb[(size_t)n * 256 + lane * 4] = xo;
    float p[8];
    #pragma unroll
    for (int v = 0; v < 8; ++v) {
        float4 wv = *(const float4*)&wsd1[v * 256 + lane * 4];
        p[v] = xv.x * wv.x + xv.y * wv.y + xv.z * wv.z + xv.w * wv.w;
    }
    #pragma unroll
    for (int v = 0; v < 8; ++v)
        #pragma unroll
        for (int s = 1; s < 64; s <<= 1) p[v] += __shfl_xor(p[v], s);
    if (lane == 0) {
        #pragma unroll
        for (int h = 0; h < 4; ++h) {
            as1_[n * 4 + h] = p[2 * h];
            ad1_[n * 4 + h] = p[2 * h + 1];
        }
    }
}

// ---------------------------------------------------------------------------
// Single-block exclusive scan (offs, cur) + global per-head max of as1_.
// ---------------------------------------------------------------------------
__global__ __launch_bounds__(1024) void scan_gmax(
    const int* __restrict__ cnt, int* __restrict__ offs, int* __restrict__ cur,
    const float* __restrict__ as1_, float* __restrict__ gmax1, int n)
{
    constexpr int CHUNK = 20;
    int t = threadIdx.x;
    int base = t * CHUNK;
    int v[CHUNK];
    int s = 0;
    #pragma unroll
    for (int i = 0; i < CHUNK; ++i) {
        int idx = base + i;
        int xv = (idx < n) ? cnt[idx] : 0;
        v[i] = s; s += xv;
    }
    int lane = t & 63, w = t >> 6;
    int sc = s;
    #pragma unroll
    for (int d = 1; d < 64; d <<= 1) {
        int o = __shfl_up(sc, d);
        if (lane >= d) sc += o;
    }
    __shared__ int wt[16], wb[17];
    __shared__ float gsm[16][4];
    if (lane == 63) wt[w] = sc;
    __syncthreads();
    if (t == 0) {
        int acc = 0;
        for (int i = 0; i < 16; ++i) { wb[i] = acc; acc += wt[i]; }
        wb[16] = acc;
    }
    __syncthreads();
    int ebase = wb[w] + (sc - s);
    #pragma unroll
    for (int i = 0; i < CHUNK; ++i) {
        int idx = base + i;
        if (idx < n) {
            int o = ebase + v[i];
            offs[idx] = o;
            cur[idx]  = o;
        }
    }
    if (t == 0) offs[n] = wb[16];

    float lm0 = -1e30f, lm1 = -1e30f, lm2 = -1e30f, lm3 = -1e30f;
    for (int i = t; i < n; i += 1024) {
        float4 a = *(const float4*)&as1_[(size_t)i * 4];
        lm0 = fmaxf(lm0, a.x); lm1 = fmaxf(lm1, a.y);
        lm2 = fmaxf(lm2, a.z); lm3 = fmaxf(lm3, a.w);
    }
    #pragma unroll
    for (int d = 1; d < 64; d <<= 1) {
        lm0 = fmaxf(lm0, __shfl_xor(lm0, d));
        lm1 = fmaxf(lm1, __shfl_xor(lm1, d));
        lm2 = fmaxf(lm2, __shfl_xor(lm2, d));
        lm3 = fmaxf(lm3, __shfl_xor(lm3, d));
    }
    if (lane == 0) {
        gsm[w][0] = lm0; gsm[w][1] = lm1; gsm[w][2] = lm2; gsm[w][3] = lm3;
    }
    __syncthreads();
    if (t == 0) {
        float m0 = -1e30f, m1 = -1e30f, m2 = -1e30f, m3 = -1e30f;
        for (int i = 0; i < 16; ++i) {
            m0 = fmaxf(m0, gsm[i][0]); m1 = fmaxf(m1, gsm[i][1]);
            m2 = fmaxf(m2, gsm[i][2]); m3 = fmaxf(m3, gsm[i][3]);
        }
        gmax1[0] = m0; gmax1[1] = m1; gmax1[2] = m2; gmax1[3] = m3;
    }
}

// ---------------------------------------------------------------------------
// Scatter: store the SOURCE node per CSR slot.
// ---------------------------------------------------------------------------
__global__ void scatter_kernel(const int* __restrict__ ei, int* __restrict__ cur,
                               int* __restrict__ srcs, int ET, int E0)
{
    int e = blockIdx.x * blockDim.x + threadIdx.x;
    if (e >= ET) return;
    int d = (e < E0) ? ei[E0 + e] : (e - E0);
    int s = (e < E0) ? ei[e] : (e - E0);
    int pos = atomicAdd(&cur[d], 1);
    srcs[pos] = s;
}

// ---------------------------------------------------------------------------
// Aggregate-x, two-phase per 64-edge chunk (wave per dst node, 4/block).
// ---------------------------------------------------------------------------
__global__ __launch_bounds__(256) void aggx_kernel(
    const __bf16* __restrict__ xb, const int* __restrict__ offs,
    const int* __restrict__ srcs,
    const float* __restrict__ as1_, const float* __restrict__ ad1_,
    const float* __restrict__ gmax1,
    __bf16* __restrict__ aggx, int N)
{
    __shared__ float w4s[4][64][4];
    __shared__ int   sidx[4][64];
    int wave = threadIdx.x >> 6, lane = threadIdx.x & 63;
    int n = blockIdx.x * 4 + wave;
    if (n >= N) return;
    int s0 = offs[n], s1 = offs[n + 1];
    float4 adv = *(const float4*)&ad1_[(size_t)n * 4];
    float m0 = lrelu(gmax1[0] + adv.x);
    float m1 = lrelu(gmax1[1] + adv.y);
    float m2 = lrelu(gmax1[2] + adv.z);
    float m3 = lrelu(gmax1[3] + adv.w);

    float d0 = 0.f, d1 = 0.f, d2 = 0.f, d3 = 0.f;
    float a0[4] = {0.f,0.f,0.f,0.f}, a1[4] = {0.f,0.f,0.f,0.f};
    float a2[4] = {0.f,0.f,0.f,0.f}, a3[4] = {0.f,0.f,0.f,0.f};
    const __bf16* xbase = xb + lane * 4;

    for (int base = s0; base < s1; base += 64) {
        int cnt = min(64, s1 - base);
        if (lane < cnt) {
            int s = srcs[base + lane];
            float4 av = *(const float4*)&as1_[(size_t)s * 4];
            float w0 = __expf(lrelu(av.x + adv.x) - m0);
            float w1 = __expf(lrelu(av.y + adv.y) - m1);
            float w2 = __expf(lrelu(av.z + adv.z) - m2);
            float w3 = __expf(lrelu(av.w + adv.w) - m3);
            d0 += w0; d1 += w1; d2 += w2; d3 += w3;
            sidx[wave][lane] = s;
            w4s[wave][lane][0] = w0; w4s[wave][lane][1] = w1;
            w4s[wave][lane][2] = w2; w4s[wave][lane][3] = w3;
        }
        int j = 0;
        for (; j + 7 < cnt; j += 8) {
            int s_[8]; float4 w_[8]; bf16x4 xv_[8];
            #pragma unroll
            for (int i = 0; i < 8; ++i) {
                s_[i] = sidx[wave][j + i];
                w_[i] = *(const float4*)&w4s[wave][j + i][0];
            }
            #pragma unroll
            for (int i = 0; i < 8; ++i)
                xv_[i] = *(const bf16x4*)(xbase + (size_t)s_[i] * 256);
            #pragma unroll
            for (int i = 0; i < 8; ++i) {
                float xf[4];
                #pragma unroll
                for (int c = 0; c < 4; ++c) xf[c] = (float)xv_[i][c];
                #pragma unroll
                for (int c = 0; c < 4; ++c) {
                    a0[c] = fmaf(w_[i].x, xf[c], a0[c]);
                    a1[c] = fmaf(w_[i].y, xf[c], a1[c]);
                    a2[c] = fmaf(w_[i].z, xf[c], a2[c]);
                    a3[c] = fmaf(w_[i].w, xf[c], a3[c]);
                }
            }
        }
        for (; j < cnt; ++j) {
            int s = sidx[wave][j];
            float4 w = *(const float4*)&w4s[wave][j][0];
            bf16x4 xv = *(const bf16x4*)(xbase + (size_t)s * 256);
            float xf[4];
            #pragma unroll
            for (int c = 0; c < 4; ++c) xf[c] = (float)xv[c];
            #pragma unroll
            for (int c = 0; c < 4; ++c) {
                a0[c] = fmaf(w.x, xf[c], a0[c]);
                a1[c] = fmaf(w.y, xf[c], a1[c]);
                a2[c] = fmaf(w.z, xf[c], a2[c]);
                a3[c] = fmaf(w.w, xf[c], a3[c]);
            }
        }
    }

    #pragma unroll
    for (int t = 1; t < 64; t <<= 1) {
        d0 += __shfl_xor(d0, t);
        d1 += __shfl_xor(d1, t);
        d2 += __shfl_xor(d2, t);
        d3 += __shfl_xor(d3, t);
    }

    float i0 = 1.f / (d0 + 1e-16f);
    float i1 = 1.f / (d1 + 1e-16f);
    float i2 = 1.f / (d2 + 1e-16f);
    float i3 = 1.f / (d3 + 1e-16f);
    __bf16* obase = aggx + (size_t)n * 1024 + lane * 4;
    bf16x4 o;
    #pragma unroll
    for (int c = 0; c < 4; ++c) o[c] = (__bf16)(a0[c] * i0);
    *(bf16x4*)(obase + 0)   = o;
    #pragma unroll
    for (int c = 0; c < 4; ++c) o[c] = (__bf16)(a1[c] * i1);
    *(bf16x4*)(obase + 256) = o;
    #pragma unroll
    for (int c = 0; c < 4; ++c) o[c] = (__bf16)(a2[c] * i2);
    *(bf16x4*)(obase + 512) = o;
    #pragma unroll
    for (int c = 0; c < 4; ++c) o[c] = (__bf16)(a3[c] * i3);
    *(bf16x4*)(obase + 768) = o;
}

// ---------------------------------------------------------------------------
// Layer-2 aggregate, two-phase. Safe-bound max from gmax2.
// ---------------------------------------------------------------------------
__global__ __launch_bounds__(256) void aggregate2_kernel(
    const __bf16* __restrict__ h2b, const int* __restrict__ offs,
    const int* __restrict__ srcs,
    const float* __restrict__ as2, const float* __restrict__ ad2,
    const unsigned* __restrict__ gmax2u,
    const float* __restrict__ b2, float* __restrict__ out2, int N)
{
    __shared__ float wls[4][64];
    __shared__ int   sidx[4][64];
    int wave = threadIdx.x >> 6, lane = threadIdx.x & 63;
    int n = blockIdx.x * 4 + wave;
    if (n >= N) return;
    int s0 = offs[n], s1 = offs[n + 1];
    float adn = ad2[n];
    float m = lrelu(funkey(*gmax2u) + adn);

    float den = 0.f;
    float c0 = 0.f, c1 = 0.f;
    const __bf16* hbase = h2b + lane * 2;

    for (int base = s0; base < s1; base += 64) {
        int cnt = min(64, s1 - base);
        if (lane < cnt) {
            int s = srcs[base + lane];
            float w = __expf(lrelu(as2[s] + adn) - m);
            den += w;
            sidx[wave][lane] = s;
            wls[wave][lane]  = w;
        }
        int j = 0;
        for (; j + 7 < cnt; j += 8) {
            int s_[8]; float w_[8]; bf16x2 h_[8];
            #pragma unroll
            for (int i = 0; i < 8; ++i) {
                s_[i] = sidx[wave][j + i];
                w_[i] = wls[wave][j + i];
            }
            #pragma unroll
            for (int i = 0; i < 8; ++i)
                h_[i] = *(const bf16x2*)(hbase + (size_t)s_[i] * 128);
            #pragma unroll
            for (int i = 0; i < 8; ++i) {
                c0 = fmaf(w_[i], (float)h_[i][0], c0);
                c1 = fmaf(w_[i], (float)h_[i][1], c1);
            }
        }
        for (; j < cnt; ++j) {
            int s = sidx[wave][j];
            float w = wls[wave][j];
            bf16x2 hv = *(const bf16x2*)(hbase + (size_t)s * 128);
            c0 = fmaf(w, (float)hv[0], c0);
            c1 = fmaf(w, (float)hv[1], c1);
        }
    }

    #pragma unroll
    for (int t = 1; t < 64; t <<= 1) den += __shfl_xor(den, t);
    float inv = 1.f / (den + 1e-16f);
    float2 o;
    o.x = c0 * inv + b2[lane * 2 + 0];
    o.y = c1 * inv + b2[lane * 2 + 1];
    *(float2*)&out2[(size_t)n * 128 + lane * 2] = o;
}

// ---------------------------------------------------------------------------
// 2-stage mean pool + FC head.
// ---------------------------------------------------------------------------
#define POOL_S 16
__global__ void pool_stage1(const float* __restrict__ out2, const int* __restrict__ gstart,
                            float* __restrict__ partial, int C)
{
    int g = blockIdx.x, slice = blockIdx.y;
    int c = threadIdx.x;
    int s = gstart[g], e = gstart[g + 1];
    int len = e - s;
    int chunk = (len + POOL_S - 1) / POOL_S;
    int n0 = s + slice * chunk;
    int n1 = min(n0 + chunk, e);
    float acc = 0.f;
    for (int n = n0; n < n1; ++n) acc += out2[(size_t)n * C + c];
    partial[((size_t)g * POOL_S + slice) * C + c] = acc;
}

__global__ __launch_bounds__(128) void pool_head(
    const float* __restrict__ partial, const int* __restrict__ gstart,
    const float* __restrict__ fc1W, const float* __restrict__ fc1b,
    const float* __restrict__ fc2W, const float* __restrict__ fc2b,
    float* __restrict__ out)
{
    int g = blockIdx.x;
    int t = threadIdx.x;
    __shared__ float pl[128];
    float acc = 0.f;
    #pragma unroll
    for (int s = 0; s < POOL_S; ++s)
        acc += partial[((size_t)g * POOL_S + s) * 128 + t];
    float cntf = (float)(gstart[g + 1] - gstart[g]);
    pl[t] = acc / fmaxf(cntf, 1.0f);
    __syncthreads();
    if (t < 64) {
        float v = 0.f;
        for (int c = 0; c < 128; ++c)
            v += pl[c] * fc1W[c * 64 + t];
        v = fmaxf(v + fc1b[t], 0.f) * fc2W[t];
        #pragma unroll
        for (int s = 32; s > 0; s >>= 1) v += __shfl_down(v, s);
        if (t == 0) out[g] = v + fc2b[0];
    }
}

// ---------------------------------------------------------------------------
extern "C" void kernel_launch(void* const* d_in, const int* in_sizes, int n_in,
                              void* d_out, int out_size, void* d_ws, size_t ws_size,
                              hipStream_t stream)
{
    const float* x    = (const float*)d_in[0];
    const int*   ei   = (const int*)d_in[1];
    const int*   batch= (const int*)d_in[2];
    const float* W1   = (const float*)d_in[3];
    const float* as1w = (const float*)d_in[4];
    const float* ad1w = (const float*)d_in[5];
    const float* b1   = (const float*)d_in[6];
    const float* W2   = (const float*)d_in[7];
    const float* as2w = (const float*)d_in[8];
    const float* ad2w = (const float*)d_in[9];
    const float* b2   = (const float*)d_in[10];
    const float* fc1W = (const float*)d_in[11];
    const float* fc1b = (const float*)d_in[12];
    const float* fc2W = (const float*)d_in[13];
    const float* fc2b = (const float*)d_in[14];
    float* out = (float*)d_out;

    const int D = 256, C = 128, G = 64;
    const int N  = in_sizes[0] / D;        // 20000
    const int E0 = in_sizes[1] / 2;        // 160000
    const int ET = E0 + N;

    char* p = (char*)d_ws;
    auto alloc = [&](size_t bytes) -> char* {
        char* r = p;
        p += (bytes + 255) & ~(size_t)255;
        return r;
    };
    __bf16* xb    = (__bf16*)alloc((size_t)N * D * 2);
    __bf16* aggx  = (__bf16*)alloc((size_t)N * 4 * 256 * 2);
    __bf16* out1b = (__bf16*)alloc((size_t)N * 512 * 2);
    __bf16* h2b   = (__bf16*)alloc((size_t)N * C * 2);
    float*  out2  = (float*)alloc((size_t)N * C * 4);
    __bf16* w1t   = (__bf16*)alloc((size_t)256 * 512 * 2);
    __bf16* w2t   = (__bf16*)alloc((size_t)512 * 128 * 2);
    float* wsd1   = (float*)alloc(8 * 256 * 4);
    float* wsd2   = (float*)alloc(2 * 512 * 4);
    float* gmax1  = (float*)alloc(4 * 4);
    unsigned* gmax2u = (unsigned*)alloc(4);
    float* as1_   = (float*)alloc((size_t)N * 4 * 4);
    float* ad1_   = (float*)alloc((size_t)N * 4 * 4);
    float* ps_part= (float*)alloc((size_t)N * 8 * 4);
    float* pd_part= (float*)alloc((size_t)N * 8 * 4);
    float* as2    = (float*)alloc((size_t)N * 4);
    float* ad2    = (float*)alloc((size_t)N * 4);
    int*   cnt    = (int*)alloc((size_t)N * 4);
    int*   cur    = (int*)alloc((size_t)N * 4);
    int*   offs   = (int*)alloc((size_t)(N + 1) * 4);
    int*   srcs   = (int*)alloc((size_t)ET * 4);
    int*   gstart = (int*)alloc((size_t)(G + 1) * 4);
    float* partial= (float*)alloc((size_t)G * POOL_S * C * 4);

    // 1. prep
    {
        int total = 199680 + 2 * N + 1;
        prep_kernel<<<(total + 255) / 256, 256, 0, stream>>>(
            W1, W2, as1w, ad1w, as2w, ad2w, batch,
            w1t, w2t, wsd1, wsd2, gstart, cnt, gmax2u, N, G);
    }

    // 2. count (2 edges/thread) + cvtx (merged)
    {
        int CB = (ET + 511) / 512;
        count_cvtx<<<CB + N / 4, 256, 0, stream>>>(
            ei, cnt, x, wsd1, xb, as1_, ad1_, ET, E0, N, CB);
    }

    // 3. scan + global head max
    scan_gmax<<<1, 1024, 0, stream>>>(cnt, offs, cur, as1_, gmax1, N);

    // 4. scatter (stores src node per slot)
    scatter_kernel<<<(ET + 255) / 256, 256, 0, stream>>>(ei, cur, srcs, ET, E0);

    // 5. aggregate x (two-phase)
    aggx_kernel<<<(N + 3) / 4, 256, 0, stream>>>(
        xb, offs, srcs, as1_, ad1_, gmax1, aggx, N);

    // 6. layer-1 GEMM on aggregated x (64x64 tiles, 2504 blocks)
    gemm1_agg<<<dim3(8, (N + 63) / 64), 256, 0, stream>>>(
        aggx, w1t, b1, wsd2, out1b, ps_part, pd_part, N);

    // 7. layer-2 GEMM with fused sum2 (extra grid rows)
    {
        int MB = (N + 63) / 64;
        int SB = ((N + 255) / 256 + 1) / 2;
        gemm2_sum<<<dim3(2, MB + SB), 256, 0, stream>>>(
            out1b, w2t, h2b, ps_part, pd_part, as2, ad2, gmax2u, N, MB);
    }

    // 8. layer-2 aggregate (two-phase)
    aggregate2_kernel<<<(N + 3) / 4, 256, 0, stream>>>(
        h2b, offs, srcs, as2, ad2, gmax2u, b2, out2, N);

    // 9. pool + 10. head
    pool_stage1<<<dim3(G, POOL_S), C, 0, stream>>>(out2, gstart, partial, C);
    pool_head<<<G, 128, 0, stream>>>(partial, gstart, fc1W, fc1b, fc2W, fc2b, out);
}

// Round 14
// 184.952 us; speedup vs baseline: 1.1198x; 1.0994x over previous
//
#include <hip/hip_runtime.h>
#include <hip/hip_bf16.h>
#include <cstdint>
#include <cstddef>

#define NEG_SLOPE 0.2f

typedef __attribute__((ext_vector_type(8))) __bf16 bf16x8;
typedef __attribute__((ext_vector_type(4))) __bf16 bf16x4;
typedef __attribute__((ext_vector_type(2))) __bf16 bf16x2;
typedef __attribute__((ext_vector_type(4))) float  f32x4;

__device__ __forceinline__ float lrelu(float v) {
    return (v < 0.f) ? NEG_SLOPE * v : v;
}

// Order-preserving float<->uint key for deterministic atomicMax on floats.
__device__ __forceinline__ unsigned fkey(float x) {
    unsigned b = __float_as_uint(x);
    return b ^ (unsigned)(((int)b >> 31) | 0x80000000);
}
__device__ __forceinline__ float funkey(unsigned k) {
    unsigned b = (k & 0x80000000u) ? (k ^ 0x80000000u) : ~k;
    return __uint_as_float(b);
}

// ---------------------------------------------------------------------------
// Layer-2 GEMM (h2 = out1b @ w2t^T) with sum2 work fused as extra grid rows.
// ---------------------------------------------------------------------------
__global__ __launch_bounds__(256) void gemm2_sum(
    const __bf16* __restrict__ A,      // out1b [M][512]
    const __bf16* __restrict__ Bt,     // w2t [128][512]
    __bf16* __restrict__ Cout,         // h2b [M][128]
    const float* __restrict__ ps_part, const float* __restrict__ pd_part,  // [M][4]
    float* __restrict__ as2, float* __restrict__ ad2,
    unsigned* __restrict__ gmax2u,
    int M, int MB)
{
    if ((int)blockIdx.y >= MB) {
        int chunk = ((int)blockIdx.y - MB) * 2 + (int)blockIdx.x;
        int i = chunk * 256 + threadIdx.x;
        float lm = -1e30f;
        if (i < M) {
            float4 p = *(const float4*)&ps_part[(size_t)i * 4];
            float4 q = *(const float4*)&pd_part[(size_t)i * 4];
            float s = (p.x + p.y) + (p.z + p.w);
            float d = (q.x + q.y) + (q.z + q.w);
            as2[i] = s;
            ad2[i] = d;
            lm = s;
        }
        #pragma unroll
        for (int t = 1; t < 64; t <<= 1) lm = fmaxf(lm, __shfl_xor(lm, t));
        if ((threadIdx.x & 63) == 0) atomicMax(gmax2u, fkey(lm));
        return;
    }

    const int tid  = threadIdx.x;
    const int wave = tid >> 6, lane = tid & 63;
    const int wr = wave >> 1, wc = wave & 1;
    const int rowbase = blockIdx.y * 64 + wr * 32;
    const int colbase = blockIdx.x * 64 + wc * 32;
    const int l15 = lane & 15, kg = lane >> 4;
    const int K = 512, N = 128;

    size_t aoff[2], boff[2];
    #pragma unroll
    for (int mf = 0; mf < 2; ++mf) {
        int r = rowbase + mf * 16 + l15;
        if (r > M - 1) r = M - 1;
        aoff[mf] = (size_t)r * K + kg * 8;
    }
    #pragma unroll
    for (int nf = 0; nf < 2; ++nf) {
        int c = colbase + nf * 16 + l15;
        boff[nf] = (size_t)c * K + kg * 8;
    }

    f32x4 acc[2][2];
    #pragma unroll
    for (int mf = 0; mf < 2; ++mf)
        #pragma unroll
        for (int nf = 0; nf < 2; ++nf)
            acc[mf][nf] = (f32x4){0.f, 0.f, 0.f, 0.f};

    #pragma unroll 2
    for (int k0 = 0; k0 < K; k0 += 32) {
        bf16x8 af[2], bfr[2];
        #pragma unroll
        for (int mf = 0; mf < 2; ++mf)
            af[mf] = *(const bf16x8*)(A + aoff[mf] + k0);
        #pragma unroll
        for (int nf = 0; nf < 2; ++nf)
            bfr[nf] = *(const bf16x8*)(Bt + boff[nf] + k0);
        #pragma unroll
        for (int mf = 0; mf < 2; ++mf)
            #pragma unroll
            for (int nf = 0; nf < 2; ++nf)
                acc[mf][nf] = __builtin_amdgcn_mfma_f32_16x16x32_bf16(af[mf], bfr[nf], acc[mf][nf], 0, 0, 0);
    }

    #pragma unroll
    for (int mf = 0; mf < 2; ++mf)
        #pragma unroll
        for (int j = 0; j < 4; ++j) {
            int r = rowbase + mf * 16 + kg * 4 + j;
            if (r < M) {
                #pragma unroll
                for (int nf = 0; nf < 2; ++nf) {
                    int c = colbase + nf * 16 + l15;
                    Cout[(size_t)r * N + c] = (__bf16)acc[mf][nf][j];
                }
            }
        }
}

// ---------------------------------------------------------------------------
// Layer-1 GEMM on aggregated-x with LDS-staged A-tile (coalesced fetch).
// Grid (4 heads, ceil(M/64)). Block stages aggx[rowtile..+64][head][0..256]
// (64 x 256 bf16 = 32 KB, +8/row pad) via 8 coalesced 4 KB iterations, then
// 4 waves compute MF=4 x NF=2 (wave w owns cols head*128 + w*32 .. +32) with
// ds_read_b128 fragments (2-way bank alias = free). B (w1t) stays global,
// L2-hot. Epilogue: bias+relu+bf16 store + wsd2-fold -> ps/pd_part[M][4].
// ---------------------------------------------------------------------------
__global__ __launch_bounds__(256) void gemm1_agg(
    const __bf16* __restrict__ aggx,   // [N][4][256]
    const __bf16* __restrict__ w1t,    // [512][256]
    const float* __restrict__ b1, const float* __restrict__ wsd2,
    __bf16* __restrict__ out1b,        // [N][512]
    float* __restrict__ ps_part, float* __restrict__ pd_part,  // [N][4]
    int M)
{
    __shared__ __bf16 As[64][264];     // 264 = 256 + 8 pad
    __shared__ float smp[4][64], smd[4][64];

    const int head = blockIdx.x;
    const int rowtile = blockIdx.y * 64;
    const int tid  = threadIdx.x;
    const int wave = tid >> 6, lane = tid & 63;
    const int l15 = lane & 15, kg = lane >> 4;

    // ---- stage A-tile (coalesced: 32 x 16B chunks per row) ----
    #pragma unroll
    for (int it = 0; it < 8; ++it) {
        int flat  = it * 256 + tid;
        int row   = flat >> 5;           // /32
        int chunk = flat & 31;
        int gr = rowtile + row;
        if (gr > M - 1) gr = M - 1;
        bf16x8 v = *(const bf16x8*)(aggx + (size_t)gr * 1024 + head * 256 + chunk * 8);
        *(bf16x8*)&As[row][chunk * 8] = v;
    }
    __syncthreads();

    // ---- compute: wave w owns cols head*128 + w*32 .. +32 (NF=2, MF=4) ----
    size_t boff[2];
    #pragma unroll
    for (int nf = 0; nf < 2; ++nf) {
        int c = head * 128 + wave * 32 + nf * 16 + l15;
        boff[nf] = (size_t)c * 256 + kg * 8;
    }

    f32x4 acc[4][2];
    #pragma unroll
    for (int mf = 0; mf < 4; ++mf)
        #pragma unroll
        for (int nf = 0; nf < 2; ++nf)
            acc[mf][nf] = (f32x4){0.f, 0.f, 0.f, 0.f};

    #pragma unroll 2
    for (int k0 = 0; k0 < 256; k0 += 32) {
        bf16x8 af[4], bfr[2];
        #pragma unroll
        for (int mf = 0; mf < 4; ++mf)
            af[mf] = *(const bf16x8*)&As[mf * 16 + l15][k0 + kg * 8];
        #pragma unroll
        for (int nf = 0; nf < 2; ++nf)
            bfr[nf] = *(const bf16x8*)(w1t + boff[nf] + k0);
        #pragma unroll
        for (int mf = 0; mf < 4; ++mf)
            #pragma unroll
            for (int nf = 0; nf < 2; ++nf)
                acc[mf][nf] = __builtin_amdgcn_mfma_f32_16x16x32_bf16(af[mf], bfr[nf], acc[mf][nf], 0, 0, 0);
    }

    // ---- epilogue ----
    #pragma unroll
    for (int mf = 0; mf < 4; ++mf)
        #pragma unroll
        for (int j = 0; j < 4; ++j) {
            int lr = mf * 16 + kg * 4 + j;
            int r  = rowtile + lr;
            float ps = 0.f, pd = 0.f;
            #pragma unroll
            for (int nf = 0; nf < 2; ++nf) {
                int col = head * 128 + wave * 32 + nf * 16 + l15;
                float o = fmaxf(acc[mf][nf][j] + b1[col], 0.f);
                if (r < M)
                    out1b[(size_t)r * 512 + col] = (__bf16)o;
                ps = fmaf(o, wsd2[col], ps);
                pd = fmaf(o, wsd2[512 + col], pd);
            }
            #pragma unroll
            for (int t = 1; t < 16; t <<= 1) {
                ps += __shfl_xor(ps, t);
                pd += __shfl_xor(pd, t);
            }
            if (l15 == 0) {
                smp[wave][lr] = ps;
                smd[wave][lr] = pd;
            }
        }
    __syncthreads();
    if (tid < 64) {
        int r = rowtile + tid;
        if (r < M) {
            ps_part[(size_t)r * 4 + head] = (smp[0][tid] + smp[1][tid]) + (smp[2][tid] + smp[3][tid]);
            pd_part[(size_t)r * 4 + head] = (smd[0][tid] + smd[1][tid]) + (smd[2][tid] + smd[3][tid]);
        }
    }
}

// ---------------------------------------------------------------------------
// Fused prep: W transpose/convert, attn vectors, gstart, cnt zero, gmax2 init.
// ---------------------------------------------------------------------------
__global__ void prep_kernel(const float* __restrict__ W1, const float* __restrict__ W2,
                            const float* __restrict__ as1w, const float* __restrict__ ad1w,
                            const float* __restrict__ as2w, const float* __restrict__ ad2w,
                            const int* __restrict__ batch,
                            __bf16* __restrict__ w1t, __bf16* __restrict__ w2t,
                            float* __restrict__ wsd1, float* __restrict__ wsd2,
                            int* __restrict__ gstart, int* __restrict__ cnt,
                            unsigned* __restrict__ gmax2u,
                            int N, int G)
{
    int t = blockIdx.x * 256 + threadIdx.x;
    if (t < 131072) {
        int i = t;
        int k = i >> 9, n = i & 511;
        w1t[n * 256 + k] = (__bf16)W1[i];
    } else if (t < 196608) {
        int j = t - 131072;
        int k = j >> 7, n = j & 127;
        w2t[n * 512 + k] = (__bf16)W2[j];
    } else if (t < 199680) {
        int t2 = t - 196608;
        if (t2 < 2048) {
            int k = t2 >> 3, v = t2 & 7, h = v >> 1;
            const float* av = (v & 1) ? (ad1w + h * 128) : (as1w + h * 128);
            float s = 0.f;
            for (int c = 0; c < 128; ++c) s += W1[k * 512 + h * 128 + c] * av[c];
            wsd1[v * 256 + k] = s;
        } else {
            int t3 = t2 - 2048;
            int k = t3 >> 1, v = t3 & 1;
            const float* av = v ? ad2w : as2w;
            float s = 0.f;
            for (int c = 0; c < 128; ++c) s += W2[k * 128 + c] * av[c];
            wsd2[v * 512 + k] = s;
        }
    } else if (t < 199680 + N) {
        int n = t - 199680;
        int b    = batch[n];
        int prev = (n == 0) ? -1 : batch[n - 1];
        for (int g = prev + 1; g <= b; ++g) gstart[g] = n;
        if (n == N - 1) {
            for (int g = b + 1; g <= G; ++g) gstart[g] = N;
        }
    } else if (t < 199680 + 2 * N) {
        cnt[t - 199680 - N] = 0;
    } else if (t == 199680 + 2 * N) {
        *gmax2u = fkey(-1e30f);
    }
}

// ---------------------------------------------------------------------------
// Merged: edge count (2 edges/thread) + x->bf16 conversion + layer-1 scores.
// ---------------------------------------------------------------------------
__global__ __launch_bounds__(256) void count_cvtx(
    const int* __restrict__ ei, int* __restrict__ cnt,
    const float* __restrict__ x, const float* __restrict__ wsd1,
    __bf16* __restrict__ xb, float* __restrict__ as1_, float* __restrict__ ad1_,
    int ET, int E0, int N, int CB)
{
    if ((int)blockIdx.x < CB) {
        int base = (blockIdx.x * 256 + threadIdx.x) * 2;
        #pragma unroll
        for (int k = 0; k < 2; ++k) {
            int e = base + k;
            if (e < ET) {
                int d = (e < E0) ? ei[E0 + e] : (e - E0);
                atomicAdd(&cnt[d], 1);
            }
        }
        return;
    }
    int bid = blockIdx.x - CB;
    int wave = threadIdx.x >> 6, lane = threadIdx.x & 63;
    int n = bid * 4 + wave;
    if (n >= N) return;
    float4 xv = *(const float4*)&x[(size_t)n * 256 + lane * 4];
    bf16x4 xo;
    xo[0] = (__bf16)xv.x; xo[1] = (__bf16)xv.y; xo[2] = (__bf16)xv.z; xo[3] = (__bf16)xv.w;
    *(bf16x4*)&xb[(size_t)n * 256 + lane * 4] = xo;
    float p[8];
    #pragma unroll
    for (int v = 0; v < 8; ++v) {
        float4 wv = *(const float4*)&wsd1[v * 256 + lane * 4];
        p[v] = xv.x * wv.x + xv.y * wv.y + xv.z * wv.z + xv.w * wv.w;
    }
    #pragma unroll
    for (int v = 0; v < 8; ++v)
        #pragma unroll
        for (int s = 1; s < 64; s <<= 1) p[v] += __shfl_xor(p[v], s);
    if (lane == 0) {
        #pragma unroll
        for (int h = 0; h < 4; ++h) {
            as1_[n * 4 + h] = p[2 * h];
            ad1_[n * 4 + h] = p[2 * h + 1];
        }
    }
}

// ---------------------------------------------------------------------------
// Single-block exclusive scan (offs, cur) + global per-head max of as1_.
// ---------------------------------------------------------------------------
__global__ __launch_bounds__(1024) void scan_gmax(
    const int* __restrict__ cnt, int* __restrict__ offs, int* __restrict__ cur,
    const float* __restrict__ as1_, float* __restrict__ gmax1, int n)
{
    constexpr int CHUNK = 20;
    int t = threadIdx.x;
    int base = t * CHUNK;
    int v[CHUNK];
    int s = 0;
    #pragma unroll
    for (int i = 0; i < CHUNK; ++i) {
        int idx = base + i;
        int xv = (idx < n) ? cnt[idx] : 0;
        v[i] = s; s += xv;
    }
    int lane = t & 63, w = t >> 6;
    int sc = s;
    #pragma unroll
    for (int d = 1; d < 64; d <<= 1) {
        int o = __shfl_up(sc, d);
        if (lane >= d) sc += o;
    }
    __shared__ int wt[16], wb[17];
    __shared__ float gsm[16][4];
    if (lane == 63) wt[w] = sc;
    __syncthreads();
    if (t == 0) {
        int acc = 0;
        for (int i = 0; i < 16; ++i) { wb[i] = acc; acc += wt[i]; }
        wb[16] = acc;
    }
    __syncthreads();
    int ebase = wb[w] + (sc - s);
    #pragma unroll
    for (int i = 0; i < CHUNK; ++i) {
        int idx = base + i;
        if (idx < n) {
            int o = ebase + v[i];
            offs[idx] = o;
            cur[idx]  = o;
        }
    }
    if (t == 0) offs[n] = wb[16];

    float lm0 = -1e30f, lm1 = -1e30f, lm2 = -1e30f, lm3 = -1e30f;
    for (int i = t; i < n; i += 1024) {
        float4 a = *(const float4*)&as1_[(size_t)i * 4];
        lm0 = fmaxf(lm0, a.x); lm1 = fmaxf(lm1, a.y);
        lm2 = fmaxf(lm2, a.z); lm3 = fmaxf(lm3, a.w);
    }
    #pragma unroll
    for (int d = 1; d < 64; d <<= 1) {
        lm0 = fmaxf(lm0, __shfl_xor(lm0, d));
        lm1 = fmaxf(lm1, __shfl_xor(lm1, d));
        lm2 = fmaxf(lm2, __shfl_xor(lm2, d));
        lm3 = fmaxf(lm3, __shfl_xor(lm3, d));
    }
    if (lane == 0) {
        gsm[w][0] = lm0; gsm[w][1] = lm1; gsm[w][2] = lm2; gsm[w][3] = lm3;
    }
    __syncthreads();
    if (t == 0) {
        float m0 = -1e30f, m1 = -1e30f, m2 = -1e30f, m3 = -1e30f;
        for (int i = 0; i < 16; ++i) {
            m0 = fmaxf(m0, gsm[i][0]); m1 = fmaxf(m1, gsm[i][1]);
            m2 = fmaxf(m2, gsm[i][2]); m3 = fmaxf(m3, gsm[i][3]);
        }
        gmax1[0] = m0; gmax1[1] = m1; gmax1[2] = m2; gmax1[3] = m3;
    }
}

// ---------------------------------------------------------------------------
// Scatter: store the SOURCE node per CSR slot.
// ---------------------------------------------------------------------------
__global__ void scatter_kernel(const int* __restrict__ ei, int* __restrict__ cur,
                               int* __restrict__ srcs, int ET, int E0)
{
    int e = blockIdx.x * blockDim.x + threadIdx.x;
    if (e >= ET) return;
    int d = (e < E0) ? ei[E0 + e] : (e - E0);
    int s = (e < E0) ? ei[e] : (e - E0);
    int pos = atomicAdd(&cur[d], 1);
    srcs[pos] = s;
}

// ---------------------------------------------------------------------------
// Aggregate-x, two-phase per 64-edge chunk (wave per dst node, 4/block).
// ---------------------------------------------------------------------------
__global__ __launch_bounds__(256) void aggx_kernel(
    const __bf16* __restrict__ xb, const int* __restrict__ offs,
    const int* __restrict__ srcs,
    const float* __restrict__ as1_, const float* __restrict__ ad1_,
    const float* __restrict__ gmax1,
    __bf16* __restrict__ aggx, int N)
{
    __shared__ float w4s[4][64][4];
    __shared__ int   sidx[4][64];
    int wave = threadIdx.x >> 6, lane = threadIdx.x & 63;
    int n = blockIdx.x * 4 + wave;
    if (n >= N) return;
    int s0 = offs[n], s1 = offs[n + 1];
    float4 adv = *(const float4*)&ad1_[(size_t)n * 4];
    float m0 = lrelu(gmax1[0] + adv.x);
    float m1 = lrelu(gmax1[1] + adv.y);
    float m2 = lrelu(gmax1[2] + adv.z);
    float m3 = lrelu(gmax1[3] + adv.w);

    float d0 = 0.f, d1 = 0.f, d2 = 0.f, d3 = 0.f;
    float a0[4] = {0.f,0.f,0.f,0.f}, a1[4] = {0.f,0.f,0.f,0.f};
    float a2[4] = {0.f,0.f,0.f,0.f}, a3[4] = {0.f,0.f,0.f,0.f};
    const __bf16* xbase = xb + lane * 4;

    for (int base = s0; base < s1; base += 64) {
        int cnt = min(64, s1 - base);
        if (lane < cnt) {
            int s = srcs[base + lane];
            float4 av = *(const float4*)&as1_[(size_t)s * 4];
            float w0 = __expf(lrelu(av.x + adv.x) - m0);
            float w1 = __expf(lrelu(av.y + adv.y) - m1);
            float w2 = __expf(lrelu(av.z + adv.z) - m2);
            float w3 = __expf(lrelu(av.w + adv.w) - m3);
            d0 += w0; d1 += w1; d2 += w2; d3 += w3;
            sidx[wave][lane] = s;
            w4s[wave][lane][0] = w0; w4s[wave][lane][1] = w1;
            w4s[wave][lane][2] = w2; w4s[wave][lane][3] = w3;
        }
        int j = 0;
        for (; j + 7 < cnt; j += 8) {
            int s_[8]; float4 w_[8]; bf16x4 xv_[8];
            #pragma unroll
            for (int i = 0; i < 8; ++i) {
                s_[i] = sidx[wave][j + i];
                w_[i] = *(const float4*)&w4s[wave][j + i][0];
            }
            #pragma unroll
            for (int i = 0; i < 8; ++i)
                xv_[i] = *(const bf16x4*)(xbase + (size_t)s_[i] * 256);
            #pragma unroll
            for (int i = 0; i < 8; ++i) {
                float xf[4];
                #pragma unroll
                for (int c = 0; c < 4; ++c) xf[c] = (float)xv_[i][c];
                #pragma unroll
                for (int c = 0; c < 4; ++c) {
                    a0[c] = fmaf(w_[i].x, xf[c], a0[c]);
                    a1[c] = fmaf(w_[i].y, xf[c], a1[c]);
                    a2[c] = fmaf(w_[i].z, xf[c], a2[c]);
                    a3[c] = fmaf(w_[i].w, xf[c], a3[c]);
                }
            }
        }
        for (; j < cnt; ++j) {
            int s = sidx[wave][j];
            float4 w = *(const float4*)&w4s[wave][j][0];
            bf16x4 xv = *(const bf16x4*)(xbase + (size_t)s * 256);
            float xf[4];
            #pragma unroll
            for (int c = 0; c < 4; ++c) xf[c] = (float)xv[c];
            #pragma unroll
            for (int c = 0; c < 4; ++c) {
                a0[c] = fmaf(w.x, xf[c], a0[c]);
                a1[c] = fmaf(w.y, xf[c], a1[c]);
                a2[c] = fmaf(w.z, xf[c], a2[c]);
                a3[c] = fmaf(w.w, xf[c], a3[c]);
            }
        }
    }

    #pragma unroll
    for (int t = 1; t < 64; t <<= 1) {
        d0 += __shfl_xor(d0, t);
        d1 += __shfl_xor(d1, t);
        d2 += __shfl_xor(d2, t);
        d3 += __shfl_xor(d3, t);
    }

    float i0 = 1.f / (d0 + 1e-16f);
    float i1 = 1.f / (d1 + 1e-16f);
    float i2 = 1.f / (d2 + 1e-16f);
    float i3 = 1.f / (d3 + 1e-16f);
    __bf16* obase = aggx + (size_t)n * 1024 + lane * 4;
    bf16x4 o;
    #pragma unroll
    for (int c = 0; c < 4; ++c) o[c] = (__bf16)(a0[c] * i0);
    *(bf16x4*)(obase + 0)   = o;
    #pragma unroll
    for (int c = 0; c < 4; ++c) o[c] = (__bf16)(a1[c] * i1);
    *(bf16x4*)(obase + 256) = o;
    #pragma unroll
    for (int c = 0; c < 4; ++c) o[c] = (__bf16)(a2[c] * i2);
    *(bf16x4*)(obase + 512) = o;
    #pragma unroll
    for (int c = 0; c < 4; ++c) o[c] = (__bf16)(a3[c] * i3);
    *(bf16x4*)(obase + 768) = o;
}

// ---------------------------------------------------------------------------
// Layer-2 aggregate, two-phase. Safe-bound max from gmax2.
// ---------------------------------------------------------------------------
__global__ __launch_bounds__(256) void aggregate2_kernel(
    const __bf16* __restrict__ h2b, const int* __restrict__ offs,
    const int* __restrict__ srcs,
    const float* __restrict__ as2, const float* __restrict__ ad2,
    const unsigned* __restrict__ gmax2u,
    const float* __restrict__ b2, float* __restrict__ out2, int N)
{
    __shared__ float wls[4][64];
    __shared__ int   sidx[4][64];
    int wave = threadIdx.x >> 6, lane = threadIdx.x & 63;
    int n = blockIdx.x * 4 + wave;
    if (n >= N) return;
    int s0 = offs[n], s1 = offs[n + 1];
    float adn = ad2[n];
    float m = lrelu(funkey(*gmax2u) + adn);

    float den = 0.f;
    float c0 = 0.f, c1 = 0.f;
    const __bf16* hbase = h2b + lane * 2;

    for (int base = s0; base < s1; base += 64) {
        int cnt = min(64, s1 - base);
        if (lane < cnt) {
            int s = srcs[base + lane];
            float w = __expf(lrelu(as2[s] + adn) - m);
            den += w;
            sidx[wave][lane] = s;
            wls[wave][lane]  = w;
        }
        int j = 0;
        for (; j + 7 < cnt; j += 8) {
            int s_[8]; float w_[8]; bf16x2 h_[8];
            #pragma unroll
            for (int i = 0; i < 8; ++i) {
                s_[i] = sidx[wave][j + i];
                w_[i] = wls[wave][j + i];
            }
            #pragma unroll
            for (int i = 0; i < 8; ++i)
                h_[i] = *(const bf16x2*)(hbase + (size_t)s_[i] * 128);
            #pragma unroll
            for (int i = 0; i < 8; ++i) {
                c0 = fmaf(w_[i], (float)h_[i][0], c0);
                c1 = fmaf(w_[i], (float)h_[i][1], c1);
            }
        }
        for (; j < cnt; ++j) {
            int s = sidx[wave][j];
            float w = wls[wave][j];
            bf16x2 hv = *(const bf16x2*)(hbase + (size_t)s * 128);
            c0 = fmaf(w, (float)hv[0], c0);
            c1 = fmaf(w, (float)hv[1], c1);
        }
    }

    #pragma unroll
    for (int t = 1; t < 64; t <<= 1) den += __shfl_xor(den, t);
    float inv = 1.f / (den + 1e-16f);
    float2 o;
    o.x = c0 * inv + b2[lane * 2 + 0];
    o.y = c1 * inv + b2[lane * 2 + 1];
    *(float2*)&out2[(size_t)n * 128 + lane * 2] = o;
}

// ---------------------------------------------------------------------------
// 2-stage mean pool + FC head.
// ---------------------------------------------------------------------------
#define POOL_S 16
__global__ void pool_stage1(const float* __restrict__ out2, const int* __restrict__ gstart,
                            float* __restrict__ partial, int C)
{
    int g = blockIdx.x, slice = blockIdx.y;
    int c = threadIdx.x;
    int s = gstart[g], e = gstart[g + 1];
    int len = e - s;
    int chunk = (len + POOL_S - 1) / POOL_S;
    int n0 = s + slice * chunk;
    int n1 = min(n0 + chunk, e);
    float acc = 0.f;
    for (int n = n0; n < n1; ++n) acc += out2[(size_t)n * C + c];
    partial[((size_t)g * POOL_S + slice) * C + c] = acc;
}

__global__ __launch_bounds__(128) void pool_head(
    const float* __restrict__ partial, const int* __restrict__ gstart,
    const float* __restrict__ fc1W, const float* __restrict__ fc1b,
    const float* __restrict__ fc2W, const float* __restrict__ fc2b,
    float* __restrict__ out)
{
    int g = blockIdx.x;
    int t = threadIdx.x;
    __shared__ float pl[128];
    float acc = 0.f;
    #pragma unroll
    for (int s = 0; s < POOL_S; ++s)
        acc += partial[((size_t)g * POOL_S + s) * 128 + t];
    float cntf = (float)(gstart[g + 1] - gstart[g]);
    pl[t] = acc / fmaxf(cntf, 1.0f);
    __syncthreads();
    if (t < 64) {
        float v = 0.f;
        for (int c = 0; c < 128; ++c)
            v += pl[c] * fc1W[c * 64 + t];
        v = fmaxf(v + fc1b[t], 0.f) * fc2W[t];
        #pragma unroll
        for (int s = 32; s > 0; s >>= 1) v += __shfl_down(v, s);
        if (t == 0) out[g] = v + fc2b[0];
    }
}

// ---------------------------------------------------------------------------
extern "C" void kernel_launch(void* const* d_in, const int* in_sizes, int n_in,
                              void* d_out, int out_size, void* d_ws, size_t ws_size,
                              hipStream_t stream)
{
    const float* x    = (const float*)d_in[0];
    const int*   ei   = (const int*)d_in[1];
    const int*   batch= (const int*)d_in[2];
    const float* W1   = (const float*)d_in[3];
    const float* as1w = (const float*)d_in[4];
    const float* ad1w = (const float*)d_in[5];
    const float* b1   = (const float*)d_in[6];
    const float* W2   = (const float*)d_in[7];
    const float* as2w = (const float*)d_in[8];
    const float* ad2w = (const float*)d_in[9];
    const float* b2   = (const float*)d_in[10];
    const float* fc1W = (const float*)d_in[11];
    const float* fc1b = (const float*)d_in[12];
    const float* fc2W = (const float*)d_in[13];
    const float* fc2b = (const float*)d_in[14];
    float* out = (float*)d_out;

    const int D = 256, C = 128, G = 64;
    const int N  = in_sizes[0] / D;        // 20000
    const int E0 = in_sizes[1] / 2;        // 160000
    const int ET = E0 + N;

    char* p = (char*)d_ws;
    auto alloc = [&](size_t bytes) -> char* {
        char* r = p;
        p += (bytes + 255) & ~(size_t)255;
        return r;
    };
    __bf16* xb    = (__bf16*)alloc((size_t)N * D * 2);
    __bf16* aggx  = (__bf16*)alloc((size_t)N * 4 * 256 * 2);
    __bf16* out1b = (__bf16*)alloc((size_t)N * 512 * 2);
    __bf16* h2b   = (__bf16*)alloc((size_t)N * C * 2);
    float*  out2  = (float*)alloc((size_t)N * C * 4);
    __bf16* w1t   = (__bf16*)alloc((size_t)256 * 512 * 2);
    __bf16* w2t   = (__bf16*)alloc((size_t)512 * 128 * 2);
    float* wsd1   = (float*)alloc(8 * 256 * 4);
    float* wsd2   = (float*)alloc(2 * 512 * 4);
    float* gmax1  = (float*)alloc(4 * 4);
    unsigned* gmax2u = (unsigned*)alloc(4);
    float* as1_   = (float*)alloc((size_t)N * 4 * 4);
    float* ad1_   = (float*)alloc((size_t)N * 4 * 4);
    float* ps_part= (float*)alloc((size_t)N * 4 * 4);
    float* pd_part= (float*)alloc((size_t)N * 4 * 4);
    float* as2    = (float*)alloc((size_t)N * 4);
    float* ad2    = (float*)alloc((size_t)N * 4);
    int*   cnt    = (int*)alloc((size_t)N * 4);
    int*   cur    = (int*)alloc((size_t)N * 4);
    int*   offs   = (int*)alloc((size_t)(N + 1) * 4);
    int*   srcs   = (int*)alloc((size_t)ET * 4);
    int*   gstart = (int*)alloc((size_t)(G + 1) * 4);
    float* partial= (float*)alloc((size_t)G * POOL_S * C * 4);

    // 1. prep
    {
        int total = 199680 + 2 * N + 1;
        prep_kernel<<<(total + 255) / 256, 256, 0, stream>>>(
            W1, W2, as1w, ad1w, as2w, ad2w, batch,
            w1t, w2t, wsd1, wsd2, gstart, cnt, gmax2u, N, G);
    }

    // 2. count (2 edges/thread) + cvtx (merged)
    {
        int CB = (ET + 511) / 512;
        count_cvtx<<<CB + N / 4, 256, 0, stream>>>(
            ei, cnt, x, wsd1, xb, as1_, ad1_, ET, E0, N, CB);
    }

    // 3. scan + global head max
    scan_gmax<<<1, 1024, 0, stream>>>(cnt, offs, cur, as1_, gmax1, N);

    // 4. scatter (stores src node per slot)
    scatter_kernel<<<(ET + 255) / 256, 256, 0, stream>>>(ei, cur, srcs, ET, E0);

    // 5. aggregate x (two-phase)
    aggx_kernel<<<(N + 3) / 4, 256, 0, stream>>>(
        xb, offs, srcs, as1_, ad1_, gmax1, aggx, N);

    // 6. layer-1 GEMM on aggregated x (LDS-staged A, 1252 blocks)
    gemm1_agg<<<dim3(4, (N + 63) / 64), 256, 0, stream>>>(
        aggx, w1t, b1, wsd2, out1b, ps_part, pd_part, N);

    // 7. layer-2 GEMM with fused sum2 (extra grid rows)
    {
        int MB = (N + 63) / 64;
        int SB = ((N + 255) / 256 + 1) / 2;
        gemm2_sum<<<dim3(2, MB + SB), 256, 0, stream>>>(
            out1b, w2t, h2b, ps_part, pd_part, as2, ad2, gmax2u, N, MB);
    }

    // 8. layer-2 aggregate (two-phase)
    aggregate2_kernel<<<(N + 3) / 4, 256, 0, stream>>>(
        h2b, offs, srcs, as2, ad2, gmax2u, b2, out2, N);

    // 9. pool + 10. head
    pool_stage1<<<dim3(G, POOL_S), C, 0, stream>>>(out2, gstart, partial, C);
    pool_head<<<G, 128, 0, stream>>>(partial, gstart, fc1W, fc1b, fc2W, fc2b, out);
}